// Round 4
// baseline (529.749 us; speedup 1.0000x reference)
//
#include <hip/hip_runtime.h>

static constexpr int T_LEN = 512;

__device__ __forceinline__ float fsigm(float x) {
    return __builtin_amdgcn_rcpf(1.0f + __expf(-x));
}
__device__ __forceinline__ float ftanh(float x) {
    return 1.0f - 2.0f * __builtin_amdgcn_rcpf(1.0f + __expf(2.0f * x));
}
// Rotate by 1 lane within each 16-lane row, at VALU speed (no DS op).
__device__ __forceinline__ float ror1(float v) {
    int i = __builtin_bit_cast(int, v);
    i = __builtin_amdgcn_mov_dpp(i, 0x121, 0xf, 0xf, true);  // row_ror:1
    return __builtin_bit_cast(float, i);
}

// Block = 256 threads = 4 waves, 8 batches. Waves 0,1: layer-0; waves 2,3:
// layer-1 skewed one 4-step group behind. h distributed 1 unit/lane;
// recurrent matvecs via DPP row_ror systolic with rotation-permuted weights.
// KEY CHANGE vs R3: no __syncthreads in the loop. Barrier = raw s_barrier +
// s_waitcnt lgkmcnt(0) ONLY (global prefetches stay in flight), and only
// once per 4 steps (8-slot LDS ring). x prefetch ring deepened to 4 steps.
__global__ __launch_bounds__(256, 1) void gru2_pipe(
    const float* __restrict__ x,
    const float* __restrict__ Wih0, const float* __restrict__ Whh0,
    const float* __restrict__ bih0, const float* __restrict__ bhh0,
    const float* __restrict__ Wih1, const float* __restrict__ Whh1,
    const float* __restrict__ bih1, const float* __restrict__ bhh1,
    const float* __restrict__ fcw,  const float* __restrict__ fcb,
    float* __restrict__ out)
{
    const int tid  = threadIdx.x;
    const int w    = tid >> 6;        // wave in block (0..3)
    const int lane = tid & 63;
    const int j    = lane & 15;       // unit index
    const int bb   = (w & 1) * 4 + (lane >> 4);  // batch within block (0..7)
    const int b    = blockIdx.x * 8 + bb;
    const bool isL0 = (w < 2);

    __shared__ float h0buf[8][8][16];   // 4 KB ring: [step&7][bb][unit]

    // rotation-direction probe (direction-agnostic weight permutation)
    const int d = (((int)ror1((float)j)) - j) & 15;

    // ---- per-lane weights ----
    float wbig[3][32];   // L0: W_ih0 rows (32, natural); L1: W_ih1 rotated (16)
    float wrec[3][16];   // rotated W_hh rows
    float b_r, b_z, b_in, b_hn;

    if (isL0) {
#pragma unroll
        for (int g = 0; g < 3; ++g) {
            const int row = g * 16 + j;
#pragma unroll
            for (int m = 0; m < 32; ++m)
                wbig[g][m] = Wih0[row * 32 + m];
#pragma unroll
            for (int m = 0; m < 16; ++m)
                wrec[g][m] = Whh0[row * 16 + ((j + m * d) & 15)];
        }
        b_r  = bih0[j]      + bhh0[j];
        b_z  = bih0[16 + j] + bhh0[16 + j];
        b_in = bih0[32 + j];
        b_hn = bhh0[32 + j];
    } else {
#pragma unroll
        for (int g = 0; g < 3; ++g) {
            const int row = g * 16 + j;
#pragma unroll
            for (int m = 0; m < 16; ++m) {
                wbig[g][m] = Wih1[row * 16 + ((j + m * d) & 15)];
                wrec[g][m] = Whh1[row * 16 + ((j + m * d) & 15)];
            }
        }
        b_r  = bih1[j]      + bhh1[j];
        b_z  = bih1[16 + j] + bhh1[16 + j];
        b_in = bih1[32 + j];
        b_hn = bhh1[32 + j];
    }

    float hs = 0.f;   // L0: h0_j ; L1: h1_j (distributed state)

    const float* xbase = x + (size_t)b * T_LEN * 32;

    // ---- 4-deep x prefetch ring (L0 waves only): buffer k holds step 4g+k ----
    float4 xb0[8], xb1[8], xb2[8], xb3[8];
    if (isL0) {
#pragma unroll
        for (int q = 0; q < 8; ++q) {
            xb0[q] = *(const float4*)(xbase + 0 * 32 + 4 * q);
            xb1[q] = *(const float4*)(xbase + 1 * 32 + 4 * q);
            xb2[q] = *(const float4*)(xbase + 2 * 32 + 4 * q);
            xb3[q] = *(const float4*)(xbase + 3 * 32 + 4 * q);
        }
    }

    auto l0_step = [&](float4 (&xb)[8], int i) {
        float xr = 0.f, xz = 0.f, xn = 0.f;
#pragma unroll
        for (int q = 0; q < 8; ++q) {
            float4 v = xb[q];
            xr = fmaf(wbig[0][4*q+0], v.x, xr);
            xr = fmaf(wbig[0][4*q+1], v.y, xr);
            xr = fmaf(wbig[0][4*q+2], v.z, xr);
            xr = fmaf(wbig[0][4*q+3], v.w, xr);
            xz = fmaf(wbig[1][4*q+0], v.x, xz);
            xz = fmaf(wbig[1][4*q+1], v.y, xz);
            xz = fmaf(wbig[1][4*q+2], v.z, xz);
            xz = fmaf(wbig[1][4*q+3], v.w, xz);
            xn = fmaf(wbig[2][4*q+0], v.x, xn);
            xn = fmaf(wbig[2][4*q+1], v.y, xn);
            xn = fmaf(wbig[2][4*q+2], v.z, xn);
            xn = fmaf(wbig[2][4*q+3], v.w, xn);
        }
        // prefetch t = i+4 into the buffer just consumed (stays in flight
        // across barriers now — only lgkmcnt is drained there)
        const int t4 = (i + 4 <= T_LEN - 1) ? (i + 4) : (T_LEN - 1);
#pragma unroll
        for (int q = 0; q < 8; ++q)
            xb[q] = *(const float4*)(xbase + (size_t)t4 * 32 + 4 * q);

        // recurrent dots via DPP systolic rotation of h0
        float ar = 0.f, az = 0.f, an = 0.f, tt = hs;
#pragma unroll
        for (int m = 0; m < 16; ++m) {
            ar = fmaf(wrec[0][m], tt, ar);
            az = fmaf(wrec[1][m], tt, az);
            an = fmaf(wrec[2][m], tt, an);
            if (m < 15) tt = ror1(tt);
        }

        float r = fsigm(xr + ar + b_r);
        float z = fsigm(xz + az + b_z);
        float n = ftanh(xn + b_in + r * (an + b_hn));
        hs = fmaf(z, hs - n, n);

        h0buf[i & 7][bb][j] = hs;
    };

    auto l1_step = [&](int i) {   // computes h1[i], reads h0[i]
        float u = h0buf[i & 7][bb][j];
        float yr = 0.f, yz = 0.f, yn = 0.f;
        float hr = 0.f, hz = 0.f, hn = 0.f;
        float vv = hs;
#pragma unroll
        for (int m = 0; m < 16; ++m) {
            yr = fmaf(wbig[0][m], u, yr);
            yz = fmaf(wbig[1][m], u, yz);
            yn = fmaf(wbig[2][m], u, yn);
            hr = fmaf(wrec[0][m], vv, hr);
            hz = fmaf(wrec[1][m], vv, hz);
            hn = fmaf(wrec[2][m], vv, hn);
            if (m < 15) { u = ror1(u); vv = ror1(vv); }
        }
        float r = fsigm(yr + hr + b_r);
        float z = fsigm(yz + hz + b_z);
        float n = ftanh(yn + b_in + r * (hn + b_hn));
        hs = fmaf(z, hs - n, n);
    };

    // ---- grouped pipelined loop: per iter, L0 does 4 steps (group g),
    // L1 does the 4 steps of group g-1. One barrier per group. ----
#pragma unroll 1
    for (int g = 0; g < 129; ++g) {
        if (isL0) {
            if (g < 128) {
                const int s0 = 4 * g;
                l0_step(xb0, s0);
                l0_step(xb1, s0 + 1);
                l0_step(xb2, s0 + 2);
                l0_step(xb3, s0 + 3);
            }
        } else {
            if (g > 0) {
                const int s0 = 4 * (g - 1);
                l1_step(s0);
                l1_step(s0 + 1);
                l1_step(s0 + 2);
                l1_step(s0 + 3);
            }
        }
        // LDS-visibility barrier WITHOUT vmcnt drain: global prefetches
        // continue across it. Memory clobber pins ds ops on the right side.
        asm volatile("s_waitcnt lgkmcnt(0)\n\ts_barrier" ::: "memory");
    }

    // ---- FC on final h1 (L1 waves hold it distributed) ----
    if (!isL0) {
        float p = fcw[j] * hs;
        p += __shfl_xor(p, 1);
        p += __shfl_xor(p, 2);
        p += __shfl_xor(p, 4);
        p += __shfl_xor(p, 8);
        if (j == 0) out[b] = p + fcb[0];
    }
}

extern "C" void kernel_launch(void* const* d_in, const int* in_sizes, int n_in,
                              void* d_out, int out_size, void* d_ws, size_t ws_size,
                              hipStream_t stream) {
    const float* x    = (const float*)d_in[0];
    const float* Wih0 = (const float*)d_in[1];
    const float* Whh0 = (const float*)d_in[2];
    const float* bih0 = (const float*)d_in[3];
    const float* bhh0 = (const float*)d_in[4];
    const float* Wih1 = (const float*)d_in[5];
    const float* Whh1 = (const float*)d_in[6];
    const float* bih1 = (const float*)d_in[7];
    const float* bhh1 = (const float*)d_in[8];
    const float* fcw  = (const float*)d_in[9];
    const float* fcb  = (const float*)d_in[10];

    // 2048 batches, 8 per block -> 256 blocks x 256 threads (1 block/CU)
    gru2_pipe<<<256, 256, 0, stream>>>(x, Wih0, Whh0, bih0, bhh0,
                                       Wih1, Whh1, bih1, bhh1, fcw, fcb,
                                       (float*)d_out);
}

// Round 5
// 192.701 us; speedup vs baseline: 2.7491x; 2.7491x over previous
//
#include <hip/hip_runtime.h>

static constexpr int T_LEN = 512;

typedef float v2f __attribute__((ext_vector_type(2)));

__device__ __forceinline__ float fsigm(float x) {
    return __builtin_amdgcn_rcpf(1.0f + __expf(-x));
}
__device__ __forceinline__ float ftanh(float x) {
    return 1.0f - 2.0f * __builtin_amdgcn_rcpf(1.0f + __expf(2.0f * x));
}
template <int CTRL>
__device__ __forceinline__ float rotf(float v) {
    return __builtin_bit_cast(float,
        __builtin_amdgcn_mov_dpp(__builtin_bit_cast(int, v), CTRL, 0xf, 0xf, true));
}
// rotate both halves of a packed pair by 2 lanes within the 16-lane row
__device__ __forceinline__ v2f rot2(v2f p) {
    v2f r;
    r.x = rotf<0x122>(p.x);
    r.y = rotf<0x122>(p.y);
    return r;
}

// Block = 256 threads = 4 waves, 8 batches. Waves 0,1: layer-0; waves 2,3:
// layer-1 one 4-step group behind. h distributed 1 unit/lane; ALL matvecs are
// DPP-rotation systolic with rotation-permuted weights, expressed as packed
// f32 pairs (v_pk_fma_f32). x is lane-distributed too (2 VGPR/step, not 32 —
// R4's spill fix). Barrier = s_waitcnt lgkmcnt(0) + s_barrier only, once per
// 4 steps; global prefetches stay in flight across it.
__global__ __launch_bounds__(256, 1) void gru2_pipe(
    const float* __restrict__ x,
    const float* __restrict__ Wih0, const float* __restrict__ Whh0,
    const float* __restrict__ bih0, const float* __restrict__ bhh0,
    const float* __restrict__ Wih1, const float* __restrict__ Whh1,
    const float* __restrict__ bih1, const float* __restrict__ bhh1,
    const float* __restrict__ fcw,  const float* __restrict__ fcb,
    float* __restrict__ out)
{
    const int tid  = threadIdx.x;
    const int w    = tid >> 6;                    // wave in block (0..3)
    const int lane = tid & 63;
    const int j    = lane & 15;                   // unit index
    const int bb   = (w & 1) * 4 + (lane >> 4);   // batch within block (0..7)
    const int b    = blockIdx.x * 8 + bb;
    const bool isL0 = (w < 2);

    __shared__ float h0buf[8][8][16];   // 4 KB ring: [step&7][bb][unit]

    // rotation-direction probes (robust to ror encoding/direction)
    const int d1 = (((int)rotf<0x121>((float)j)) - j) & 15;  // shift of ror:1
    const int d2 = (((int)rotf<0x122>((float)j)) - j) & 15;  // shift of ror:2

    // ---- packed weights, one array for both roles ----
    // L0: W[g][k]     = (Whh0[row, c(2k)],    Whh0[row, c(2k+1)])      k=0..7
    //     W[g][8+k]   = (Wih0[row, c(2k)],    Wih0[row, c(2k+1)])
    //     W[g][16+k]  = (Wih0[row, 16+c(2k)], Wih0[row, 16+c(2k+1)])
    //     where c(2k)=(j+k*d2)&15, c(2k+1)=(j+d1+k*d2)&15
    // L1: W[g][m]     = (Wih1[row, cm], Whh1[row, cm]), cm=(j+m*d1)&15, m=0..15
    v2f W[3][24];
    float b_r, b_z, b_in, b_hn;

    if (isL0) {
#pragma unroll
        for (int g = 0; g < 3; ++g) {
            const int row = g * 16 + j;
#pragma unroll
            for (int k = 0; k < 8; ++k) {
                const int c0 = (j + k * d2) & 15;
                const int c1 = (j + d1 + k * d2) & 15;
                W[g][k].x      = Whh0[row * 16 + c0];
                W[g][k].y      = Whh0[row * 16 + c1];
                W[g][8 + k].x  = Wih0[row * 32 + c0];
                W[g][8 + k].y  = Wih0[row * 32 + c1];
                W[g][16 + k].x = Wih0[row * 32 + 16 + c0];
                W[g][16 + k].y = Wih0[row * 32 + 16 + c1];
            }
        }
        b_r  = bih0[j]      + bhh0[j];
        b_z  = bih0[16 + j] + bhh0[16 + j];
        b_in = bih0[32 + j];
        b_hn = bhh0[32 + j];
    } else {
#pragma unroll
        for (int g = 0; g < 3; ++g) {
            const int row = g * 16 + j;
#pragma unroll
            for (int m = 0; m < 16; ++m) {
                const int cm = (j + m * d1) & 15;
                W[g][m].x = Wih1[row * 16 + cm];
                W[g][m].y = Whh1[row * 16 + cm];
            }
        }
        b_r  = bih1[j]      + bhh1[j];
        b_z  = bih1[16 + j] + bhh1[16 + j];
        b_in = bih1[32 + j];
        b_hn = bhh1[32 + j];
    }

    float hs = 0.f;   // L0: h0_j ; L1: h1_j (distributed state)

    const float* xbase = x + (size_t)b * T_LEN * 32;

    // ---- 4-step x ring, lane-distributed: 2 VGPR per step ----
    float xl0, xl1, xl2, xl3, xh0, xh1, xh2, xh3;
    if (isL0) {
        xl0 = xbase[0 * 32 + j];  xh0 = xbase[0 * 32 + 16 + j];
        xl1 = xbase[1 * 32 + j];  xh1 = xbase[1 * 32 + 16 + j];
        xl2 = xbase[2 * 32 + j];  xh2 = xbase[2 * 32 + 16 + j];
        xl3 = xbase[3 * 32 + j];  xh3 = xbase[3 * 32 + 16 + j];
    }

    auto l0_step = [&](float& lo, float& hi, int i) {
        const float x0 = lo, x1 = hi;
        // prefetch step i+4 into the just-freed slot (stays in flight
        // across the group barrier — only lgkmcnt is drained there)
        const int t4 = (i + 4 < T_LEN) ? (i + 4) : (T_LEN - 1);
        lo = xbase[t4 * 32 + j];
        hi = xbase[t4 * 32 + 16 + j];

        v2f ptt, px0, px1;
        ptt.x = hs;  ptt.y = rotf<0x121>(hs);
        px0.x = x0;  px0.y = rotf<0x121>(x0);
        px1.x = x1;  px1.y = rotf<0x121>(x1);
        v2f ar = {0.f, 0.f}, az = {0.f, 0.f};
        v2f axn = {0.f, 0.f}, aan = {0.f, 0.f};
#pragma unroll
        for (int k = 0; k < 8; ++k) {
            ar  = __builtin_elementwise_fma(W[0][8 + k],  px0, ar);
            az  = __builtin_elementwise_fma(W[1][8 + k],  px0, az);
            axn = __builtin_elementwise_fma(W[2][8 + k],  px0, axn);
            ar  = __builtin_elementwise_fma(W[0][16 + k], px1, ar);
            az  = __builtin_elementwise_fma(W[1][16 + k], px1, az);
            axn = __builtin_elementwise_fma(W[2][16 + k], px1, axn);
            ar  = __builtin_elementwise_fma(W[0][k], ptt, ar);
            az  = __builtin_elementwise_fma(W[1][k], ptt, az);
            aan = __builtin_elementwise_fma(W[2][k], ptt, aan);
            if (k < 7) { ptt = rot2(ptt); px0 = rot2(px0); px1 = rot2(px1); }
        }
        const float r = fsigm(ar.x + ar.y + b_r);
        const float z = fsigm(az.x + az.y + b_z);
        const float n = ftanh(axn.x + axn.y + b_in + r * (aan.x + aan.y + b_hn));
        hs = fmaf(z, hs - n, n);
        h0buf[i & 7][bb][j] = hs;
    };

    auto l1_step = [&](float u) {
        v2f puv;
        puv.x = u;   // h0[t] contribution (W_ih1 side)
        puv.y = hs;  // h1[t-1] contribution (W_hh1 side)
        v2f ar = {0.f, 0.f}, az = {0.f, 0.f}, an2 = {0.f, 0.f};
#pragma unroll
        for (int m = 0; m < 16; ++m) {
            ar  = __builtin_elementwise_fma(W[0][m], puv, ar);
            az  = __builtin_elementwise_fma(W[1][m], puv, az);
            an2 = __builtin_elementwise_fma(W[2][m], puv, an2);
            if (m < 15) {
                puv.x = rotf<0x121>(puv.x);
                puv.y = rotf<0x121>(puv.y);
            }
        }
        const float r = fsigm(ar.x + ar.y + b_r);
        const float z = fsigm(az.x + az.y + b_z);
        const float n = ftanh(an2.x + b_in + r * (an2.y + b_hn));
        hs = fmaf(z, hs - n, n);
    };

    // ---- grouped pipelined loop: L0 does group g, L1 does group g-1,
    // one lgkm-only barrier per group ----
#pragma unroll 1
    for (int g = 0; g < 129; ++g) {
        if (isL0) {
            if (g < 128) {
                const int s0 = 4 * g;
                l0_step(xl0, xh0, s0);
                l0_step(xl1, xh1, s0 + 1);
                l0_step(xl2, xh2, s0 + 2);
                l0_step(xl3, xh3, s0 + 3);
            }
        } else {
            if (g > 0) {
                const int s0 = 4 * (g - 1);
                // batch the 4 LDS reads so their lgkm waits amortize
                const float u0 = h0buf[(s0 + 0) & 7][bb][j];
                const float u1 = h0buf[(s0 + 1) & 7][bb][j];
                const float u2 = h0buf[(s0 + 2) & 7][bb][j];
                const float u3 = h0buf[(s0 + 3) & 7][bb][j];
                l1_step(u0);
                l1_step(u1);
                l1_step(u2);
                l1_step(u3);
            }
        }
        // LDS-visibility barrier WITHOUT vmcnt drain: x prefetches live on.
        asm volatile("s_waitcnt lgkmcnt(0)\n\ts_barrier" ::: "memory");
    }

    // ---- FC on final h1 (L1 waves hold it distributed) ----
    if (!isL0) {
        float p = fcw[j] * hs;
        p += __shfl_xor(p, 1);
        p += __shfl_xor(p, 2);
        p += __shfl_xor(p, 4);
        p += __shfl_xor(p, 8);
        if (j == 0) out[b] = p + fcb[0];
    }
}

extern "C" void kernel_launch(void* const* d_in, const int* in_sizes, int n_in,
                              void* d_out, int out_size, void* d_ws, size_t ws_size,
                              hipStream_t stream) {
    const float* x    = (const float*)d_in[0];
    const float* Wih0 = (const float*)d_in[1];
    const float* Whh0 = (const float*)d_in[2];
    const float* bih0 = (const float*)d_in[3];
    const float* bhh0 = (const float*)d_in[4];
    const float* Wih1 = (const float*)d_in[5];
    const float* Whh1 = (const float*)d_in[6];
    const float* bih1 = (const float*)d_in[7];
    const float* bhh1 = (const float*)d_in[8];
    const float* fcw  = (const float*)d_in[9];
    const float* fcb  = (const float*)d_in[10];

    // 2048 batches, 8 per block -> 256 blocks x 256 threads (1 block/CU)
    gru2_pipe<<<256, 256, 0, stream>>>(x, Wih0, Whh0, bih0, bhh0,
                                       Wih1, Whh1, bih1, bhh1, fcw, fcb,
                                       (float*)d_out);
}